// Round 2
// baseline (2485.098 us; speedup 1.0000x reference)
//
#include <hip/hip_runtime.h>
#include <math.h>

#define CC_ 256
#define RC_ 32
#define BB_ 4
#define NN_ 4096

// ---------------------------------------------------------------------------
// K1: fused 1x1 conv projections q,k,v
//   qT [B,N,32], kT [B,N,32], vT [B,N,256]  (n-major for attention consumption)
// Weight reads are wave-uniform -> scalar loads; x reads coalesced over n.
__global__ __launch_bounds__(256) void qkv_kernel(
    const float* __restrict__ x,
    const float* __restrict__ q_w, const float* __restrict__ q_b,
    const float* __restrict__ k_w, const float* __restrict__ k_b,
    const float* __restrict__ v_w, const float* __restrict__ v_b,
    float* __restrict__ qT, float* __restrict__ kT, float* __restrict__ vT)
{
    const int tid = threadIdx.x;
    const int n   = blockIdx.x * 256 + tid;
    const int rb  = blockIdx.y;            // 0:q 1:k 2..9:v rows (rb-2)*32
    const int b   = blockIdx.z;

    const float* W; const float* bias;
    if (rb == 0)      { W = q_w;                         bias = q_b; }
    else if (rb == 1) { W = k_w;                         bias = k_b; }
    else              { W = v_w + (size_t)(rb-2)*32*CC_; bias = v_b + (rb-2)*32; }

    const float* xb = x + (size_t)b*CC_*NN_ + n;

    float acc[32];
    #pragma unroll
    for (int r = 0; r < 32; r++) acc[r] = 0.f;

    #pragma unroll 4
    for (int cc = 0; cc < CC_; cc++) {
        float xv = xb[(size_t)cc*NN_];
        #pragma unroll
        for (int r = 0; r < 32; r++)
            acc[r] = fmaf(W[r*CC_ + cc], xv, acc[r]);
    }

    float out[32];
    #pragma unroll
    for (int r = 0; r < 32; r++) out[r] = acc[r] + bias[r];

    float* dst;
    if (rb == 0)      dst = qT + ((size_t)b*NN_ + n)*32;
    else if (rb == 1) dst = kT + ((size_t)b*NN_ + n)*32;
    else              dst = vT + ((size_t)b*NN_ + n)*CC_ + (rb-2)*32;
    #pragma unroll
    for (int u = 0; u < 8; u++)
        *(float4*)&dst[4*u] = make_float4(out[4*u], out[4*u+1], out[4*u+2], out[4*u+3]);
}

// ---------------------------------------------------------------------------
// K2: CAM energy partials: e_part[b][ns][c][d] = sum_{n in slice} x[c][n]*x[d][n]
// 64-thread blocks, 64x64 output tile, 8x8 register tile per thread.
__global__ __launch_bounds__(64) void cam_energy_kernel(
    const float* __restrict__ x, float* __restrict__ e_part)
{
    const int t  = threadIdx.x;
    const int cb = blockIdx.x >> 2, db = blockIdx.x & 3;
    const int ns = blockIdx.y;
    const int b  = blockIdx.z;
    const int c0 = cb*64, d0 = db*64;
    const int nbase = ns*256;
    const int c_l = t >> 3, d_l = t & 7;

    __shared__ float Xc[64*33];
    __shared__ float Xd[64*33];

    float acc[8][8];
    #pragma unroll
    for (int i = 0; i < 8; i++)
        #pragma unroll
        for (int j = 0; j < 8; j++) acc[i][j] = 0.f;

    for (int ch = 0; ch < 8; ch++) {
        const int n0c = nbase + ch*32;
        __syncthreads();
        for (int idx = t; idx < 512; idx += 64) {
            int row = idx >> 3, q = idx & 7;
            float4 v = *(const float4*)&x[((size_t)b*CC_ + c0+row)*NN_ + n0c + 4*q];
            Xc[row*33 + 4*q+0] = v.x; Xc[row*33 + 4*q+1] = v.y;
            Xc[row*33 + 4*q+2] = v.z; Xc[row*33 + 4*q+3] = v.w;
        }
        for (int idx = t; idx < 512; idx += 64) {
            int row = idx >> 3, q = idx & 7;
            float4 v = *(const float4*)&x[((size_t)b*CC_ + d0+row)*NN_ + n0c + 4*q];
            Xd[row*33 + 4*q+0] = v.x; Xd[row*33 + 4*q+1] = v.y;
            Xd[row*33 + 4*q+2] = v.z; Xd[row*33 + 4*q+3] = v.w;
        }
        __syncthreads();
        #pragma unroll 4
        for (int nn = 0; nn < 32; nn++) {
            float xc[8], xd[8];
            #pragma unroll
            for (int i = 0; i < 8; i++) xc[i] = Xc[(8*c_l+i)*33 + nn];
            #pragma unroll
            for (int j = 0; j < 8; j++) xd[j] = Xd[(8*d_l+j)*33 + nn];
            #pragma unroll
            for (int i = 0; i < 8; i++)
                #pragma unroll
                for (int j = 0; j < 8; j++)
                    acc[i][j] = fmaf(xc[i], xd[j], acc[i][j]);
        }
    }

    #pragma unroll
    for (int i = 0; i < 8; i++) {
        size_t rowoff = ((((size_t)b*16 + ns)*CC_) + c0 + 8*c_l + i)*CC_ + d0 + 8*d_l;
        *(float4*)&e_part[rowoff]     = make_float4(acc[i][0], acc[i][1], acc[i][2], acc[i][3]);
        *(float4*)&e_part[rowoff + 4] = make_float4(acc[i][4], acc[i][5], acc[i][6], acc[i][7]);
    }
}

// ---------------------------------------------------------------------------
// K3: CAM softmax. softmax(rowmax - e) == exp(rowmin - e)/sum  (only min matters).
// Also reduces the 16 n-split partials.
__global__ __launch_bounds__(256) void cam_softmax_kernel(
    const float* __restrict__ e_part, float* __restrict__ attn)
{
    const int c = blockIdx.x, b = blockIdx.y;
    const int d = threadIdx.x;
    const int lane = d & 63, w = d >> 6;

    float e = 0.f;
    #pragma unroll
    for (int p = 0; p < 16; p++)
        e += e_part[(((size_t)b*16 + p)*CC_ + c)*CC_ + d];

    __shared__ float red[4];
    float m = e;
    #pragma unroll
    for (int off = 32; off > 0; off >>= 1) m = fminf(m, __shfl_xor(m, off));
    if (lane == 0) red[w] = m;
    __syncthreads();
    m = fminf(fminf(red[0], red[1]), fminf(red[2], red[3]));
    __syncthreads();

    float p = __expf(m - e);
    float s = p;
    #pragma unroll
    for (int off = 32; off > 0; off >>= 1) s += __shfl_xor(s, off);
    if (lane == 0) red[w] = s;
    __syncthreads();
    s = red[0] + red[1] + red[2] + red[3];

    attn[((size_t)b*CC_ + c)*CC_ + d] = p / s;
}

// ---------------------------------------------------------------------------
// K4: CAM apply: feats[b][256+c][n] = gamma_c * sum_d attn[c][d]*x[d][n] + x[c][n]
// attn reads wave-uniform -> scalar loads.
__global__ __launch_bounds__(256) void cam_apply_kernel(
    const float* __restrict__ x, const float* __restrict__ attn,
    const float* __restrict__ gamma_c, float* __restrict__ feats)
{
    const int tid = threadIdx.x;
    const int n  = blockIdx.x * 256 + tid;
    const int c0 = blockIdx.y * 32;
    const int b  = blockIdx.z;
    const float* A  = attn + ((size_t)b*CC_ + c0)*CC_;
    const float* xb = x + (size_t)b*CC_*NN_;

    float acc[32];
    #pragma unroll
    for (int r = 0; r < 32; r++) acc[r] = 0.f;

    #pragma unroll 4
    for (int dd = 0; dd < CC_; dd++) {
        float xv = xb[(size_t)dd*NN_ + n];
        #pragma unroll
        for (int r = 0; r < 32; r++)
            acc[r] = fmaf(A[r*CC_ + dd], xv, acc[r]);
    }
    const float gc = gamma_c[0];
    #pragma unroll
    for (int r = 0; r < 32; r++)
        feats[((size_t)b*2*CC_ + CC_ + c0 + r)*NN_ + n] =
            gc*acc[r] + xb[(size_t)(c0+r)*NN_ + n];
}

// ---------------------------------------------------------------------------
// K5: PAM flash attention. q-tile 64 (block), m-tile 32, 512 threads (8 waves).
// lane<->m mapping: mm = lane&31, ih = lane>>5; wave w owns q rows 8w..8w+7.
// Output: feats[b][c][n] = gamma_p * pam_out + x   (channels 0..255)
__global__ __launch_bounds__(512) void pam_flash_kernel(
    const float* __restrict__ x, const float* __restrict__ qT,
    const float* __restrict__ kT, const float* __restrict__ vT,
    const float* __restrict__ gamma_p, float* __restrict__ feats)
{
    const int tid  = threadIdx.x;
    const int w    = tid >> 6, lane = tid & 63;
    const int n0   = blockIdx.x * 64;
    const int b    = blockIdx.y;
    const int mm   = lane & 31, ih = lane >> 5;

    __shared__ float q_t[32*64];    // q_t[r][row]
    __shared__ float k_l[32*32];    // XOR-swizzled: k[row][r] at row*32 + (r^row)
    __shared__ float P_l[64*32];    // P[row][mm], wave-private rows
    __shared__ float v_l[32*256];   // v tile, linear; reused as transpose buf [64][68]

    for (int idx = tid; idx < 2048; idx += 512) {
        int row = idx & 63, r = idx >> 6;
        q_t[r*64 + row] = qT[((size_t)b*NN_ + n0 + row)*32 + r];
    }

    float O[8][4];
    #pragma unroll
    for (int i = 0; i < 8; i++) { O[i][0]=O[i][1]=O[i][2]=O[i][3]=0.f; }
    float m_run[8], l_run[8];
    #pragma unroll
    for (int i = 0; i < 8; i++) { m_run[i] = -INFINITY; l_run[i] = 0.f; }

    for (int m0 = 0; m0 < NN_; m0 += 32) {
        __syncthreads();
        for (int idx = tid; idx < 1024; idx += 512) {
            int row = idx >> 5, r = idx & 31;
            k_l[row*32 + (r ^ row)] = kT[((size_t)b*NN_ + m0 + row)*32 + r];
        }
        for (int idx = tid; idx < 2048; idx += 512) {
            int row = idx >> 6, q = idx & 63;
            *(float4*)&v_l[row*256 + 4*q] =
                *(const float4*)&vT[((size_t)b*NN_ + m0 + row)*CC_ + 4*q];
        }
        __syncthreads();

        // S[ii] = energy[n0 + 8w + 4ih + ii][m0 + mm]
        float S[4] = {0.f, 0.f, 0.f, 0.f};
        #pragma unroll 8
        for (int r = 0; r < 32; r++) {
            float kv = k_l[mm*32 + (r ^ mm)];
            float4 q4 = *(const float4*)&q_t[r*64 + 8*w + 4*ih];
            S[0] = fmaf(q4.x, kv, S[0]);
            S[1] = fmaf(q4.y, kv, S[1]);
            S[2] = fmaf(q4.z, kv, S[2]);
            S[3] = fmaf(q4.w, kv, S[3]);
        }

        // online softmax (half-wave = 32 lanes hold one row)
        float tmax[4], tsum[4], pv[4];
        #pragma unroll
        for (int ii = 0; ii < 4; ii++) {
            float mloc = S[ii];
            #pragma unroll
            for (int off = 16; off > 0; off >>= 1) mloc = fmaxf(mloc, __shfl_xor(mloc, off));
            tmax[ii] = mloc;
        }
        float scale[8];
        #pragma unroll
        for (int i = 0; i < 8; i++) {
            float mt = __shfl(tmax[i & 3], (i >> 2) << 5);
            float mn = fmaxf(m_run[i], mt);
            scale[i] = __expf(m_run[i] - mn);
            m_run[i] = mn;
        }
        #pragma unroll
        for (int ii = 0; ii < 4; ii++) {
            pv[ii] = __expf(S[ii] - m_run[4*ih + ii]);
            float sl = pv[ii];
            #pragma unroll
            for (int off = 16; off > 0; off >>= 1) sl += __shfl_xor(sl, off);
            tsum[ii] = sl;
        }
        #pragma unroll
        for (int i = 0; i < 8; i++) {
            float ts = __shfl(tsum[i & 3], (i >> 2) << 5);
            l_run[i] = l_run[i]*scale[i] + ts;
            #pragma unroll
            for (int j = 0; j < 4; j++) O[i][j] *= scale[i];
        }
        #pragma unroll
        for (int ii = 0; ii < 4; ii++)
            P_l[(8*w + 4*ih + ii)*32 + mm] = pv[ii];
        // P_l rows are wave-private; same-array ds ordering handled by compiler

        // PV: O[i][j] += sum_mm P[row_i][mm] * v[mm][4*lane + j]
        #pragma unroll 2
        for (int mmb = 0; mmb < 32; mmb += 4) {
            float V[4][4];
            #pragma unroll
            for (int u = 0; u < 4; u++) {
                float4 vv = *(const float4*)&v_l[(mmb+u)*256 + 4*lane];
                V[u][0]=vv.x; V[u][1]=vv.y; V[u][2]=vv.z; V[u][3]=vv.w;
            }
            #pragma unroll
            for (int i = 0; i < 8; i++) {
                float4 p4 = *(const float4*)&P_l[(8*w + i)*32 + mmb];
                float P4[4] = {p4.x, p4.y, p4.z, p4.w};
                #pragma unroll
                for (int u = 0; u < 4; u++)
                    #pragma unroll
                    for (int j = 0; j < 4; j++)
                        O[i][j] = fmaf(P4[u], V[u][j], O[i][j]);
            }
        }
    }

    #pragma unroll
    for (int i = 0; i < 8; i++) {
        float inv = 1.f / l_run[i];
        #pragma unroll
        for (int j = 0; j < 4; j++) O[i][j] *= inv;
    }

    // transpose through LDS (reuse v_l as [64 c][68]) for coalesced stores
    const float gp = gamma_p[0];
    float* tile = v_l;
    for (int cb = 0; cb < 4; cb++) {
        __syncthreads();
        if ((lane >> 4) == cb) {
            int dl = lane & 15;
            #pragma unroll
            for (int i = 0; i < 8; i++)
                #pragma unroll
                for (int j = 0; j < 4; j++)
                    tile[(4*dl + j)*68 + 8*w + i] = O[i][j];
        }
        __syncthreads();
        for (int idx = tid; idx < 4096; idx += 512) {
            int cc2 = idx >> 6, nn = idx & 63;
            int chn = 64*cb + cc2;
            feats[((size_t)b*2*CC_ + chn)*NN_ + n0 + nn] =
                gp * tile[cc2*68 + nn] + x[((size_t)b*CC_ + chn)*NN_ + n0 + nn];
        }
    }
}

// ---------------------------------------------------------------------------
// K6: fuse conv3x3 (512 -> 256, pad 1, no bias). y -> d_out.
// 16x64 spatial tile, 8 out-chans x 4 px per thread, ic chunks of 4.
__global__ __launch_bounds__(256) void conv_kernel(
    const float* __restrict__ feats, const float* __restrict__ fuse_w,
    float* __restrict__ y)
{
    const int tid = threadIdx.x;
    const int ty = tid >> 4, tx = tid & 15;
    const int tile_y = blockIdx.x * 16;
    const int o0 = blockIdx.y * 8;
    const int b = blockIdx.z;

    __shared__ float patch[4*18*66];
    __shared__ float wl[4*9*8];

    float acc[8][4];
    #pragma unroll
    for (int oo = 0; oo < 8; oo++) { acc[oo][0]=acc[oo][1]=acc[oo][2]=acc[oo][3]=0.f; }

    for (int i0 = 0; i0 < 512; i0 += 4) {
        __syncthreads();
        for (int idx = tid; idx < 4752; idx += 256) {
            int ic = idx / 1188, rem = idx - ic*1188;
            int yy = rem / 66, xx = rem - yy*66;
            int gy = tile_y - 1 + yy, gx = xx - 1;
            float v = 0.f;
            if ((unsigned)gy < 64u && (unsigned)gx < 64u)
                v = feats[(((size_t)b*512 + i0 + ic)*64 + gy)*64 + gx];
            patch[(ic*18 + yy)*66 + xx] = v;
        }
        for (int idx = tid; idx < 288; idx += 256) {
            int oo = idx / 36, rem = idx - oo*36;
            int ic = rem / 9, k = rem - ic*9;
            wl[(ic*9 + k)*8 + oo] = fuse_w[((size_t)(o0+oo)*512 + i0+ic)*9 + k];
        }
        __syncthreads();

        #pragma unroll
        for (int ic = 0; ic < 4; ic++) {
            float px[3][6];
            #pragma unroll
            for (int dy = 0; dy < 3; dy++)
                #pragma unroll
                for (int h = 0; h < 3; h++) {
                    float2 t2 = *(const float2*)&patch[(ic*18 + ty+dy)*66 + 4*tx + 2*h];
                    px[dy][2*h] = t2.x; px[dy][2*h+1] = t2.y;
                }
            #pragma unroll
            for (int dy = 0; dy < 3; dy++)
                #pragma unroll
                for (int dx = 0; dx < 3; dx++) {
                    const int k = dy*3 + dx;
                    float4 wa = *(const float4*)&wl[(ic*9 + k)*8 + 0];
                    float4 wb = *(const float4*)&wl[(ic*9 + k)*8 + 4];
                    float w8[8] = {wa.x, wa.y, wa.z, wa.w, wb.x, wb.y, wb.z, wb.w};
                    #pragma unroll
                    for (int oo = 0; oo < 8; oo++)
                        #pragma unroll
                        for (int p = 0; p < 4; p++)
                            acc[oo][p] = fmaf(w8[oo], px[dy][dx+p], acc[oo][p]);
                }
        }
    }

    #pragma unroll
    for (int oo = 0; oo < 8; oo++)
        *(float4*)&y[(((size_t)b*CC_ + o0+oo)*64 + tile_y+ty)*64 + 4*tx] =
            make_float4(acc[oo][0], acc[oo][1], acc[oo][2], acc[oo][3]);
}

// ---------------------------------------------------------------------------
// K7: BN batch stats per channel (no atomics: one block per channel).
// stats[c] = scale, stats[256+c] = shift
__global__ __launch_bounds__(256) void bn_stats_kernel(
    const float* __restrict__ y, const float* __restrict__ bn_scale,
    const float* __restrict__ bn_bias, float* __restrict__ stats)
{
    const int c = blockIdx.x;
    const int tid = threadIdx.x;
    const int lane = tid & 63, w = tid >> 6;
    float s = 0.f, q = 0.f;
    for (int b = 0; b < 4; b++) {
        const float4* p = (const float4*)(y + ((size_t)b*CC_ + c)*NN_);
        for (int i = tid; i < 1024; i += 256) {
            float4 v = p[i];
            s += v.x + v.y + v.z + v.w;
            q += v.x*v.x + v.y*v.y + v.z*v.z + v.w*v.w;
        }
    }
    #pragma unroll
    for (int off = 32; off > 0; off >>= 1) { s += __shfl_xor(s, off); q += __shfl_xor(q, off); }
    __shared__ float rs[4], rq[4];
    if (lane == 0) { rs[w] = s; rq[w] = q; }
    __syncthreads();
    if (tid == 0) {
        float S = rs[0]+rs[1]+rs[2]+rs[3];
        float Q = rq[0]+rq[1]+rq[2]+rq[3];
        const float inv_n = 1.f / 16384.f;
        float mean = S * inv_n;
        float var  = Q * inv_n - mean*mean;
        float sc = bn_scale[c] * rsqrtf(var + 1e-5f);
        stats[c]       = sc;
        stats[CC_ + c] = bn_bias[c] - mean * sc;
    }
}

// K8: BN apply + ReLU, in place on d_out.
__global__ __launch_bounds__(256) void bn_apply_kernel(
    float* __restrict__ y, const float* __restrict__ stats)
{
    const int f = blockIdx.x*256 + threadIdx.x;   // float4 index, 1048576 total
    const int c = (f >> 10) & 255;
    const float sc = stats[c], sh = stats[CC_ + c];
    float4 v = ((float4*)y)[f];
    v.x = fmaxf(fmaf(v.x, sc, sh), 0.f);
    v.y = fmaxf(fmaf(v.y, sc, sh), 0.f);
    v.z = fmaxf(fmaf(v.z, sc, sh), 0.f);
    v.w = fmaxf(fmaf(v.w, sc, sh), 0.f);
    ((float4*)y)[f] = v;
}

// ---------------------------------------------------------------------------
extern "C" void kernel_launch(void* const* d_in, const int* in_sizes, int n_in,
                              void* d_out, int out_size, void* d_ws, size_t ws_size,
                              hipStream_t stream)
{
    const float* x        = (const float*)d_in[0];
    const float* q_w      = (const float*)d_in[1];
    const float* q_b      = (const float*)d_in[2];
    const float* k_w      = (const float*)d_in[3];
    const float* k_b      = (const float*)d_in[4];
    const float* v_w      = (const float*)d_in[5];
    const float* v_b      = (const float*)d_in[6];
    const float* gamma_p  = (const float*)d_in[7];
    const float* gamma_c  = (const float*)d_in[8];
    const float* fuse_w   = (const float*)d_in[9];
    const float* bn_scale = (const float*)d_in[10];
    const float* bn_bias  = (const float*)d_in[11];
    float* out = (float*)d_out;

    float* ws     = (float*)d_ws;
    float* qT     = ws;                                   //  524288
    float* kT     = qT     + (size_t)BB_*NN_*32;          //  524288
    float* vT     = kT     + (size_t)BB_*NN_*32;          // 4194304
    float* feats  = vT     + (size_t)BB_*NN_*CC_;         // 8388608
    float* e_part = feats  + (size_t)BB_*2*CC_*NN_;       // 4194304
    float* attn   = e_part + (size_t)BB_*16*CC_*CC_;      //  262144
    float* stats  = attn   + (size_t)BB_*CC_*CC_;         //     512
    // total ~71.3 MB of workspace

    hipLaunchKernelGGL(qkv_kernel, dim3(16,10,BB_), dim3(256), 0, stream,
                       x, q_w, q_b, k_w, k_b, v_w, v_b, qT, kT, vT);
    hipLaunchKernelGGL(cam_energy_kernel, dim3(16,16,BB_), dim3(64), 0, stream,
                       x, e_part);
    hipLaunchKernelGGL(cam_softmax_kernel, dim3(CC_,BB_), dim3(256), 0, stream,
                       e_part, attn);
    hipLaunchKernelGGL(cam_apply_kernel, dim3(16,8,BB_), dim3(256), 0, stream,
                       x, attn, gamma_c, feats);
    hipLaunchKernelGGL(pam_flash_kernel, dim3(64,BB_), dim3(512), 0, stream,
                       x, qT, kT, vT, gamma_p, feats);
    hipLaunchKernelGGL(conv_kernel, dim3(4,32,BB_), dim3(256), 0, stream,
                       feats, fuse_w, out);
    hipLaunchKernelGGL(bn_stats_kernel, dim3(CC_), dim3(256), 0, stream,
                       out, bn_scale, bn_bias, stats);
    hipLaunchKernelGGL(bn_apply_kernel, dim3(4096), dim3(256), 0, stream,
                       out, stats);
}

// Round 3
// 1929.312 us; speedup vs baseline: 1.2881x; 1.2881x over previous
//
#include <hip/hip_runtime.h>
#include <math.h>

#define CC_ 256
#define RC_ 32
#define BB_ 4
#define NN_ 4096

// ---------------------------------------------------------------------------
// K1: fused 1x1 conv projections q,k,v
//   qT [B,N,32], kT [B,N,32], vT [B,N,256]  (n-major for attention consumption)
// Weight reads are wave-uniform -> scalar loads; x reads coalesced over n.
__global__ __launch_bounds__(256) void qkv_kernel(
    const float* __restrict__ x,
    const float* __restrict__ q_w, const float* __restrict__ q_b,
    const float* __restrict__ k_w, const float* __restrict__ k_b,
    const float* __restrict__ v_w, const float* __restrict__ v_b,
    float* __restrict__ qT, float* __restrict__ kT, float* __restrict__ vT)
{
    const int tid = threadIdx.x;
    const int n   = blockIdx.x * 256 + tid;
    const int rb  = blockIdx.y;            // 0:q 1:k 2..9:v rows (rb-2)*32
    const int b   = blockIdx.z;

    const float* W; const float* bias;
    if (rb == 0)      { W = q_w;                         bias = q_b; }
    else if (rb == 1) { W = k_w;                         bias = k_b; }
    else              { W = v_w + (size_t)(rb-2)*32*CC_; bias = v_b + (rb-2)*32; }

    const float* xb = x + (size_t)b*CC_*NN_ + n;

    float acc[32];
    #pragma unroll
    for (int r = 0; r < 32; r++) acc[r] = 0.f;

    #pragma unroll 4
    for (int cc = 0; cc < CC_; cc++) {
        float xv = xb[(size_t)cc*NN_];
        #pragma unroll
        for (int r = 0; r < 32; r++)
            acc[r] = fmaf(W[r*CC_ + cc], xv, acc[r]);
    }

    float out[32];
    #pragma unroll
    for (int r = 0; r < 32; r++) out[r] = acc[r] + bias[r];

    float* dst;
    if (rb == 0)      dst = qT + ((size_t)b*NN_ + n)*32;
    else if (rb == 1) dst = kT + ((size_t)b*NN_ + n)*32;
    else              dst = vT + ((size_t)b*NN_ + n)*CC_ + (rb-2)*32;
    #pragma unroll
    for (int u = 0; u < 8; u++)
        *(float4*)&dst[4*u] = make_float4(out[4*u], out[4*u+1], out[4*u+2], out[4*u+3]);
}

// ---------------------------------------------------------------------------
// K2: CAM energy partials: e_part[b][ns][c][d] = sum_{n in slice} x[c][n]*x[d][n]
// 64-thread blocks, 64x64 output tile, 8x8 register tile per thread.
__global__ __launch_bounds__(64) void cam_energy_kernel(
    const float* __restrict__ x, float* __restrict__ e_part)
{
    const int t  = threadIdx.x;
    const int cb = blockIdx.x >> 2, db = blockIdx.x & 3;
    const int ns = blockIdx.y;
    const int b  = blockIdx.z;
    const int c0 = cb*64, d0 = db*64;
    const int nbase = ns*256;
    const int c_l = t >> 3, d_l = t & 7;

    __shared__ float Xc[64*33];
    __shared__ float Xd[64*33];

    float acc[8][8];
    #pragma unroll
    for (int i = 0; i < 8; i++)
        #pragma unroll
        for (int j = 0; j < 8; j++) acc[i][j] = 0.f;

    for (int ch = 0; ch < 8; ch++) {
        const int n0c = nbase + ch*32;
        __syncthreads();
        for (int idx = t; idx < 512; idx += 64) {
            int row = idx >> 3, q = idx & 7;
            float4 v = *(const float4*)&x[((size_t)b*CC_ + c0+row)*NN_ + n0c + 4*q];
            Xc[row*33 + 4*q+0] = v.x; Xc[row*33 + 4*q+1] = v.y;
            Xc[row*33 + 4*q+2] = v.z; Xc[row*33 + 4*q+3] = v.w;
        }
        for (int idx = t; idx < 512; idx += 64) {
            int row = idx >> 3, q = idx & 7;
            float4 v = *(const float4*)&x[((size_t)b*CC_ + d0+row)*NN_ + n0c + 4*q];
            Xd[row*33 + 4*q+0] = v.x; Xd[row*33 + 4*q+1] = v.y;
            Xd[row*33 + 4*q+2] = v.z; Xd[row*33 + 4*q+3] = v.w;
        }
        __syncthreads();
        #pragma unroll 4
        for (int nn = 0; nn < 32; nn++) {
            float xc[8], xd[8];
            #pragma unroll
            for (int i = 0; i < 8; i++) xc[i] = Xc[(8*c_l+i)*33 + nn];
            #pragma unroll
            for (int j = 0; j < 8; j++) xd[j] = Xd[(8*d_l+j)*33 + nn];
            #pragma unroll
            for (int i = 0; i < 8; i++)
                #pragma unroll
                for (int j = 0; j < 8; j++)
                    acc[i][j] = fmaf(xc[i], xd[j], acc[i][j]);
        }
    }

    #pragma unroll
    for (int i = 0; i < 8; i++) {
        size_t rowoff = ((((size_t)b*16 + ns)*CC_) + c0 + 8*c_l + i)*CC_ + d0 + 8*d_l;
        *(float4*)&e_part[rowoff]     = make_float4(acc[i][0], acc[i][1], acc[i][2], acc[i][3]);
        *(float4*)&e_part[rowoff + 4] = make_float4(acc[i][4], acc[i][5], acc[i][6], acc[i][7]);
    }
}

// ---------------------------------------------------------------------------
// K3: CAM softmax. softmax(rowmax - e) == exp(rowmin - e)/sum  (only min matters).
// Also reduces the 16 n-split partials.
__global__ __launch_bounds__(256) void cam_softmax_kernel(
    const float* __restrict__ e_part, float* __restrict__ attn)
{
    const int c = blockIdx.x, b = blockIdx.y;
    const int d = threadIdx.x;
    const int lane = d & 63, w = d >> 6;

    float e = 0.f;
    #pragma unroll
    for (int p = 0; p < 16; p++)
        e += e_part[(((size_t)b*16 + p)*CC_ + c)*CC_ + d];

    __shared__ float red[4];
    float m = e;
    #pragma unroll
    for (int off = 32; off > 0; off >>= 1) m = fminf(m, __shfl_xor(m, off));
    if (lane == 0) red[w] = m;
    __syncthreads();
    m = fminf(fminf(red[0], red[1]), fminf(red[2], red[3]));
    __syncthreads();

    float p = __expf(m - e);
    float s = p;
    #pragma unroll
    for (int off = 32; off > 0; off >>= 1) s += __shfl_xor(s, off);
    if (lane == 0) red[w] = s;
    __syncthreads();
    s = red[0] + red[1] + red[2] + red[3];

    attn[((size_t)b*CC_ + c)*CC_ + d] = p / s;
}

// ---------------------------------------------------------------------------
// K4: CAM apply: feats[b][256+c][n] = gamma_c * sum_d attn[c][d]*x[d][n] + x[c][n]
// attn reads wave-uniform -> scalar loads.
__global__ __launch_bounds__(256) void cam_apply_kernel(
    const float* __restrict__ x, const float* __restrict__ attn,
    const float* __restrict__ gamma_c, float* __restrict__ feats)
{
    const int tid = threadIdx.x;
    const int n  = blockIdx.x * 256 + tid;
    const int c0 = blockIdx.y * 32;
    const int b  = blockIdx.z;
    const float* A  = attn + ((size_t)b*CC_ + c0)*CC_;
    const float* xb = x + (size_t)b*CC_*NN_;

    float acc[32];
    #pragma unroll
    for (int r = 0; r < 32; r++) acc[r] = 0.f;

    #pragma unroll 4
    for (int dd = 0; dd < CC_; dd++) {
        float xv = xb[(size_t)dd*NN_ + n];
        #pragma unroll
        for (int r = 0; r < 32; r++)
            acc[r] = fmaf(A[r*CC_ + dd], xv, acc[r]);
    }
    const float gc = gamma_c[0];
    #pragma unroll
    for (int r = 0; r < 32; r++)
        feats[((size_t)b*2*CC_ + CC_ + c0 + r)*NN_ + n] =
            gc*acc[r] + xb[(size_t)(c0+r)*NN_ + n];
}

// ---------------------------------------------------------------------------
// K5: PAM flash attention. q-tile 64 (block), m-tile 32, 512 threads (8 waves).
// lane<->m mapping: mm = lane&31, ih = lane>>5; wave w owns q rows 8w..8w+7.
// Output: feats[b][c][n] = gamma_p * pam_out + x   (channels 0..255)
__global__ __launch_bounds__(512) void pam_flash_kernel(
    const float* __restrict__ x, const float* __restrict__ qT,
    const float* __restrict__ kT, const float* __restrict__ vT,
    const float* __restrict__ gamma_p, float* __restrict__ feats)
{
    const int tid  = threadIdx.x;
    const int w    = tid >> 6, lane = tid & 63;
    const int n0   = blockIdx.x * 64;
    const int b    = blockIdx.y;
    const int mm   = lane & 31, ih = lane >> 5;

    __shared__ float q_t[32*64];    // q_t[r][row]
    __shared__ float k_l[32*32];    // XOR-swizzled: k[row][r] at row*32 + (r^row)
    __shared__ float P_l[64*32];    // P[row][mm], wave-private rows
    __shared__ float v_l[32*256];   // v tile, linear; reused as transpose buf [64][68]

    for (int idx = tid; idx < 2048; idx += 512) {
        int row = idx & 63, r = idx >> 6;
        q_t[r*64 + row] = qT[((size_t)b*NN_ + n0 + row)*32 + r];
    }

    float O[8][4];
    #pragma unroll
    for (int i = 0; i < 8; i++) { O[i][0]=O[i][1]=O[i][2]=O[i][3]=0.f; }
    float m_run[8], l_run[8];
    #pragma unroll
    for (int i = 0; i < 8; i++) { m_run[i] = -INFINITY; l_run[i] = 0.f; }

    for (int m0 = 0; m0 < NN_; m0 += 32) {
        __syncthreads();
        for (int idx = tid; idx < 1024; idx += 512) {
            int row = idx >> 5, r = idx & 31;
            k_l[row*32 + (r ^ row)] = kT[((size_t)b*NN_ + m0 + row)*32 + r];
        }
        for (int idx = tid; idx < 2048; idx += 512) {
            int row = idx >> 6, q = idx & 63;
            *(float4*)&v_l[row*256 + 4*q] =
                *(const float4*)&vT[((size_t)b*NN_ + m0 + row)*CC_ + 4*q];
        }
        __syncthreads();

        // S[ii] = energy[n0 + 8w + 4ih + ii][m0 + mm]
        float S[4] = {0.f, 0.f, 0.f, 0.f};
        #pragma unroll 8
        for (int r = 0; r < 32; r++) {
            float kv = k_l[mm*32 + (r ^ mm)];
            float4 q4 = *(const float4*)&q_t[r*64 + 8*w + 4*ih];
            S[0] = fmaf(q4.x, kv, S[0]);
            S[1] = fmaf(q4.y, kv, S[1]);
            S[2] = fmaf(q4.z, kv, S[2]);
            S[3] = fmaf(q4.w, kv, S[3]);
        }

        // online softmax (half-wave = 32 lanes hold one row)
        float tmax[4], tsum[4], pv[4];
        #pragma unroll
        for (int ii = 0; ii < 4; ii++) {
            float mloc = S[ii];
            #pragma unroll
            for (int off = 16; off > 0; off >>= 1) mloc = fmaxf(mloc, __shfl_xor(mloc, off));
            tmax[ii] = mloc;
        }
        float scale[8];
        #pragma unroll
        for (int i = 0; i < 8; i++) {
            float mt = __shfl(tmax[i & 3], (i >> 2) << 5);
            float mn = fmaxf(m_run[i], mt);
            scale[i] = __expf(m_run[i] - mn);
            m_run[i] = mn;
        }
        #pragma unroll
        for (int ii = 0; ii < 4; ii++) {
            pv[ii] = __expf(S[ii] - m_run[4*ih + ii]);
            float sl = pv[ii];
            #pragma unroll
            for (int off = 16; off > 0; off >>= 1) sl += __shfl_xor(sl, off);
            tsum[ii] = sl;
        }
        #pragma unroll
        for (int i = 0; i < 8; i++) {
            float ts = __shfl(tsum[i & 3], (i >> 2) << 5);
            l_run[i] = l_run[i]*scale[i] + ts;
            #pragma unroll
            for (int j = 0; j < 4; j++) O[i][j] *= scale[i];
        }
        #pragma unroll
        for (int ii = 0; ii < 4; ii++)
            P_l[(8*w + 4*ih + ii)*32 + mm] = pv[ii];
        // P_l rows are wave-private; same-array ds ordering handled by compiler

        // PV: O[i][j] += sum_mm P[row_i][mm] * v[mm][4*lane + j]
        #pragma unroll 2
        for (int mmb = 0; mmb < 32; mmb += 4) {
            float V[4][4];
            #pragma unroll
            for (int u = 0; u < 4; u++) {
                float4 vv = *(const float4*)&v_l[(mmb+u)*256 + 4*lane];
                V[u][0]=vv.x; V[u][1]=vv.y; V[u][2]=vv.z; V[u][3]=vv.w;
            }
            #pragma unroll
            for (int i = 0; i < 8; i++) {
                float4 p4 = *(const float4*)&P_l[(8*w + i)*32 + mmb];
                float P4[4] = {p4.x, p4.y, p4.z, p4.w};
                #pragma unroll
                for (int u = 0; u < 4; u++)
                    #pragma unroll
                    for (int j = 0; j < 4; j++)
                        O[i][j] = fmaf(P4[u], V[u][j], O[i][j]);
            }
        }
    }

    #pragma unroll
    for (int i = 0; i < 8; i++) {
        float inv = 1.f / l_run[i];
        #pragma unroll
        for (int j = 0; j < 4; j++) O[i][j] *= inv;
    }

    // transpose through LDS (reuse v_l as [64 c][68]) for coalesced stores
    const float gp = gamma_p[0];
    float* tile = v_l;
    for (int cb = 0; cb < 4; cb++) {
        __syncthreads();
        if ((lane >> 4) == cb) {
            int dl = lane & 15;
            #pragma unroll
            for (int i = 0; i < 8; i++)
                #pragma unroll
                for (int j = 0; j < 4; j++)
                    tile[(4*dl + j)*68 + 8*w + i] = O[i][j];
        }
        __syncthreads();
        for (int idx = tid; idx < 4096; idx += 512) {
            int cc2 = idx >> 6, nn = idx & 63;
            int chn = 64*cb + cc2;
            feats[((size_t)b*2*CC_ + chn)*NN_ + n0 + nn] =
                gp * tile[cc2*68 + nn] + x[((size_t)b*CC_ + chn)*NN_ + n0 + nn];
        }
    }
}

// ---------------------------------------------------------------------------
// K6: fuse conv3x3 (512 -> 256, pad 1, no bias). feats -> y (d_out).
// v2: 8x64 spatial tile, 1024 blocks (4/CU, ~50% occ), div-free staging,
// stride-67 patch (2-way banks max), x-halo is always zero (tile spans W).
// Thread: tx = tid&15 (cols 4tx..4tx+3), ty = tid>>4; row = ty&7, och = ty>>3.
// acc[4 oc][4 px]; waves 0-1 -> oc o0..o0+3, waves 2-3 -> o0+4..o0+7.
__global__ __launch_bounds__(256, 4) void conv_kernel(
    const float* __restrict__ feats, const float* __restrict__ fuse_w,
    float* __restrict__ y)
{
    const int tid = threadIdx.x;
    const int tx = tid & 15;
    const int ty = tid >> 4;
    const int row = ty & 7;
    const int och = ty >> 3;           // 0 or 1, wave-uniform
    const int tile_y = blockIdx.x * 8;
    const int o0 = blockIdx.y * 8;
    const int b = blockIdx.z;

    __shared__ float patch[4*10*67];   // [ic][yy][67]; col0 & col65/66 stay 0
    __shared__ float wl[9*4*8];        // [k][ic][oc8]

    // one-time zero (halo columns + OOB safety); staging overwrites cols 1..64
    for (int idx = tid; idx < 4*10*67; idx += 256) patch[idx] = 0.f;

    float acc[4][4];
    #pragma unroll
    for (int oo = 0; oo < 4; oo++) { acc[oo][0]=acc[oo][1]=acc[oo][2]=acc[oo][3]=0.f; }

    const int wv   = tid >> 6;         // wave id = ic slot, 0..3
    const int lane = tid & 63;         // gx

    for (int i0 = 0; i0 < 512; i0 += 4) {
        __syncthreads();
        // stage patch: wave wv loads ic = i0+wv, rows gy = tile_y-1 .. tile_y+8
        {
            const float* src = &feats[(((size_t)b*512 + i0 + wv)*64)*64 + lane];
            float* dstl = &patch[(wv*10)*67 + lane + 1];
            #pragma unroll
            for (int k = 0; k < 10; k++) {
                int gy = tile_y - 1 + k;
                float v = 0.f;
                if ((unsigned)gy < 64u) v = src[(size_t)gy*64];
                dstl[k*67] = v;
            }
        }
        // stage weights: 288 floats, shift/mask indexing only
        for (int idx = tid; idx < 288; idx += 256) {
            int oc8 = idx & 7, rem = idx >> 3;
            int ic = rem & 3, k = rem >> 2;
            wl[(k*4 + ic)*8 + oc8] =
                fuse_w[(size_t)(o0 + oc8)*4608 + (size_t)(i0 + ic)*9 + k];
        }
        __syncthreads();

        #pragma unroll
        for (int ic = 0; ic < 4; ic++) {
            float px[3][6];
            #pragma unroll
            for (int dy = 0; dy < 3; dy++) {
                const float* pr = &patch[(ic*10 + row + dy)*67 + 4*tx];
                #pragma unroll
                for (int j = 0; j < 6; j++) px[dy][j] = pr[j];
            }
            #pragma unroll
            for (int dy = 0; dy < 3; dy++)
                #pragma unroll
                for (int dx = 0; dx < 3; dx++) {
                    float4 w4 = *(const float4*)&wl[((dy*3 + dx)*4 + ic)*8 + 4*och];
                    float wv4[4] = {w4.x, w4.y, w4.z, w4.w};
                    #pragma unroll
                    for (int oo = 0; oo < 4; oo++)
                        #pragma unroll
                        for (int p = 0; p < 4; p++)
                            acc[oo][p] = fmaf(wv4[oo], px[dy][dx + p], acc[oo][p]);
                }
        }
    }

    #pragma unroll
    for (int oo = 0; oo < 4; oo++)
        *(float4*)&y[(((size_t)b*CC_ + o0 + 4*och + oo)*64 + tile_y + row)*64 + 4*tx] =
            make_float4(acc[oo][0], acc[oo][1], acc[oo][2], acc[oo][3]);
}

// ---------------------------------------------------------------------------
// K7: BN batch stats per channel (no atomics: one block per channel).
// stats[c] = scale, stats[256+c] = shift
__global__ __launch_bounds__(256) void bn_stats_kernel(
    const float* __restrict__ y, const float* __restrict__ bn_scale,
    const float* __restrict__ bn_bias, float* __restrict__ stats)
{
    const int c = blockIdx.x;
    const int tid = threadIdx.x;
    const int lane = tid & 63, w = tid >> 6;
    float s = 0.f, q = 0.f;
    for (int b = 0; b < 4; b++) {
        const float4* p = (const float4*)(y + ((size_t)b*CC_ + c)*NN_);
        for (int i = tid; i < 1024; i += 256) {
            float4 v = p[i];
            s += v.x + v.y + v.z + v.w;
            q += v.x*v.x + v.y*v.y + v.z*v.z + v.w*v.w;
        }
    }
    #pragma unroll
    for (int off = 32; off > 0; off >>= 1) { s += __shfl_xor(s, off); q += __shfl_xor(q, off); }
    __shared__ float rs[4], rq[4];
    if (lane == 0) { rs[w] = s; rq[w] = q; }
    __syncthreads();
    if (tid == 0) {
        float S = rs[0]+rs[1]+rs[2]+rs[3];
        float Q = rq[0]+rq[1]+rq[2]+rq[3];
        const float inv_n = 1.f / 16384.f;
        float mean = S * inv_n;
        float var  = Q * inv_n - mean*mean;
        float sc = bn_scale[c] * rsqrtf(var + 1e-5f);
        stats[c]       = sc;
        stats[CC_ + c] = bn_bias[c] - mean * sc;
    }
}

// K8: BN apply + ReLU, in place on d_out.
__global__ __launch_bounds__(256) void bn_apply_kernel(
    float* __restrict__ y, const float* __restrict__ stats)
{
    const int f = blockIdx.x*256 + threadIdx.x;   // float4 index, 1048576 total
    const int c = (f >> 10) & 255;
    const float sc = stats[c], sh = stats[CC_ + c];
    float4 v = ((float4*)y)[f];
    v.x = fmaxf(fmaf(v.x, sc, sh), 0.f);
    v.y = fmaxf(fmaf(v.y, sc, sh), 0.f);
    v.z = fmaxf(fmaf(v.z, sc, sh), 0.f);
    v.w = fmaxf(fmaf(v.w, sc, sh), 0.f);
    ((float4*)y)[f] = v;
}

// ---------------------------------------------------------------------------
extern "C" void kernel_launch(void* const* d_in, const int* in_sizes, int n_in,
                              void* d_out, int out_size, void* d_ws, size_t ws_size,
                              hipStream_t stream)
{
    const float* x        = (const float*)d_in[0];
    const float* q_w      = (const float*)d_in[1];
    const float* q_b      = (const float*)d_in[2];
    const float* k_w      = (const float*)d_in[3];
    const float* k_b      = (const float*)d_in[4];
    const float* v_w      = (const float*)d_in[5];
    const float* v_b      = (const float*)d_in[6];
    const float* gamma_p  = (const float*)d_in[7];
    const float* gamma_c  = (const float*)d_in[8];
    const float* fuse_w   = (const float*)d_in[9];
    const float* bn_scale = (const float*)d_in[10];
    const float* bn_bias  = (const float*)d_in[11];
    float* out = (float*)d_out;

    float* ws     = (float*)d_ws;
    float* qT     = ws;                                   //  524288
    float* kT     = qT     + (size_t)BB_*NN_*32;          //  524288
    float* vT     = kT     + (size_t)BB_*NN_*32;          // 4194304
    float* feats  = vT     + (size_t)BB_*NN_*CC_;         // 8388608
    float* e_part = feats  + (size_t)BB_*2*CC_*NN_;       // 4194304
    float* attn   = e_part + (size_t)BB_*16*CC_*CC_;      //  262144
    float* stats  = attn   + (size_t)BB_*CC_*CC_;         //     512
    // total ~71.3 MB of workspace

    hipLaunchKernelGGL(qkv_kernel, dim3(16,10,BB_), dim3(256), 0, stream,
                       x, q_w, q_b, k_w, k_b, v_w, v_b, qT, kT, vT);
    hipLaunchKernelGGL(cam_energy_kernel, dim3(16,16,BB_), dim3(64), 0, stream,
                       x, e_part);
    hipLaunchKernelGGL(cam_softmax_kernel, dim3(CC_,BB_), dim3(256), 0, stream,
                       e_part, attn);
    hipLaunchKernelGGL(cam_apply_kernel, dim3(16,8,BB_), dim3(256), 0, stream,
                       x, attn, gamma_c, feats);
    hipLaunchKernelGGL(pam_flash_kernel, dim3(64,BB_), dim3(512), 0, stream,
                       x, qT, kT, vT, gamma_p, feats);
    hipLaunchKernelGGL(conv_kernel, dim3(8,32,BB_), dim3(256), 0, stream,
                       feats, fuse_w, out);
    hipLaunchKernelGGL(bn_stats_kernel, dim3(CC_), dim3(256), 0, stream,
                       out, bn_scale, bn_bias, stats);
    hipLaunchKernelGGL(bn_apply_kernel, dim3(4096), dim3(256), 0, stream,
                       out, stats);
}

// Round 6
// 1694.281 us; speedup vs baseline: 1.4668x; 1.1387x over previous
//
#include <hip/hip_runtime.h>
#include <math.h>

#define CC_ 256
#define RC_ 32
#define BB_ 4
#define NN_ 4096

// ---------------------------------------------------------------------------
// K1: fused 1x1 conv projections q,k,v
//   qT [B,N,32], kT [B,N,32], vT [B,N,256]  (n-major for attention consumption)
// Weight reads are wave-uniform -> scalar loads; x reads coalesced over n.
__global__ __launch_bounds__(256) void qkv_kernel(
    const float* __restrict__ x,
    const float* __restrict__ q_w, const float* __restrict__ q_b,
    const float* __restrict__ k_w, const float* __restrict__ k_b,
    const float* __restrict__ v_w, const float* __restrict__ v_b,
    float* __restrict__ qT, float* __restrict__ kT, float* __restrict__ vT)
{
    const int tid = threadIdx.x;
    const int n   = blockIdx.x * 256 + tid;
    const int rb  = blockIdx.y;            // 0:q 1:k 2..9:v rows (rb-2)*32
    const int b   = blockIdx.z;

    const float* W; const float* bias;
    if (rb == 0)      { W = q_w;                         bias = q_b; }
    else if (rb == 1) { W = k_w;                         bias = k_b; }
    else              { W = v_w + (size_t)(rb-2)*32*CC_; bias = v_b + (rb-2)*32; }

    const float* xb = x + (size_t)b*CC_*NN_ + n;

    float acc[32];
    #pragma unroll
    for (int r = 0; r < 32; r++) acc[r] = 0.f;

    #pragma unroll 4
    for (int cc = 0; cc < CC_; cc++) {
        float xv = xb[(size_t)cc*NN_];
        #pragma unroll
        for (int r = 0; r < 32; r++)
            acc[r] = fmaf(W[r*CC_ + cc], xv, acc[r]);
    }

    float out[32];
    #pragma unroll
    for (int r = 0; r < 32; r++) out[r] = acc[r] + bias[r];

    float* dst;
    if (rb == 0)      dst = qT + ((size_t)b*NN_ + n)*32;
    else if (rb == 1) dst = kT + ((size_t)b*NN_ + n)*32;
    else              dst = vT + ((size_t)b*NN_ + n)*CC_ + (rb-2)*32;
    #pragma unroll
    for (int u = 0; u < 8; u++)
        *(float4*)&dst[4*u] = make_float4(out[4*u], out[4*u+1], out[4*u+2], out[4*u+3]);
}

// ---------------------------------------------------------------------------
// K2: CAM energy partials: e_part[b][ns][c][d] = sum_{n in slice} x[c][n]*x[d][n]
// 64-thread blocks, 64x64 output tile, 8x8 register tile per thread.
__global__ __launch_bounds__(64) void cam_energy_kernel(
    const float* __restrict__ x, float* __restrict__ e_part)
{
    const int t  = threadIdx.x;
    const int cb = blockIdx.x >> 2, db = blockIdx.x & 3;
    const int ns = blockIdx.y;
    const int b  = blockIdx.z;
    const int c0 = cb*64, d0 = db*64;
    const int nbase = ns*256;
    const int c_l = t >> 3, d_l = t & 7;

    __shared__ float Xc[64*33];
    __shared__ float Xd[64*33];

    float acc[8][8];
    #pragma unroll
    for (int i = 0; i < 8; i++)
        #pragma unroll
        for (int j = 0; j < 8; j++) acc[i][j] = 0.f;

    for (int ch = 0; ch < 8; ch++) {
        const int n0c = nbase + ch*32;
        __syncthreads();
        for (int idx = t; idx < 512; idx += 64) {
            int row = idx >> 3, q = idx & 7;
            float4 v = *(const float4*)&x[((size_t)b*CC_ + c0+row)*NN_ + n0c + 4*q];
            Xc[row*33 + 4*q+0] = v.x; Xc[row*33 + 4*q+1] = v.y;
            Xc[row*33 + 4*q+2] = v.z; Xc[row*33 + 4*q+3] = v.w;
        }
        for (int idx = t; idx < 512; idx += 64) {
            int row = idx >> 3, q = idx & 7;
            float4 v = *(const float4*)&x[((size_t)b*CC_ + d0+row)*NN_ + n0c + 4*q];
            Xd[row*33 + 4*q+0] = v.x; Xd[row*33 + 4*q+1] = v.y;
            Xd[row*33 + 4*q+2] = v.z; Xd[row*33 + 4*q+3] = v.w;
        }
        __syncthreads();
        #pragma unroll 4
        for (int nn = 0; nn < 32; nn++) {
            float xc[8], xd[8];
            #pragma unroll
            for (int i = 0; i < 8; i++) xc[i] = Xc[(8*c_l+i)*33 + nn];
            #pragma unroll
            for (int j = 0; j < 8; j++) xd[j] = Xd[(8*d_l+j)*33 + nn];
            #pragma unroll
            for (int i = 0; i < 8; i++)
                #pragma unroll
                for (int j = 0; j < 8; j++)
                    acc[i][j] = fmaf(xc[i], xd[j], acc[i][j]);
        }
    }

    #pragma unroll
    for (int i = 0; i < 8; i++) {
        size_t rowoff = ((((size_t)b*16 + ns)*CC_) + c0 + 8*c_l + i)*CC_ + d0 + 8*d_l;
        *(float4*)&e_part[rowoff]     = make_float4(acc[i][0], acc[i][1], acc[i][2], acc[i][3]);
        *(float4*)&e_part[rowoff + 4] = make_float4(acc[i][4], acc[i][5], acc[i][6], acc[i][7]);
    }
}

// ---------------------------------------------------------------------------
// K3: CAM softmax. softmax(rowmax - e) == exp(rowmin - e)/sum  (only min matters).
// Also reduces the 16 n-split partials.
__global__ __launch_bounds__(256) void cam_softmax_kernel(
    const float* __restrict__ e_part, float* __restrict__ attn)
{
    const int c = blockIdx.x, b = blockIdx.y;
    const int d = threadIdx.x;
    const int lane = d & 63, w = d >> 6;

    float e = 0.f;
    #pragma unroll
    for (int p = 0; p < 16; p++)
        e += e_part[(((size_t)b*16 + p)*CC_ + c)*CC_ + d];

    __shared__ float red[4];
    float m = e;
    #pragma unroll
    for (int off = 32; off > 0; off >>= 1) m = fminf(m, __shfl_xor(m, off));
    if (lane == 0) red[w] = m;
    __syncthreads();
    m = fminf(fminf(red[0], red[1]), fminf(red[2], red[3]));
    __syncthreads();

    float p = __expf(m - e);
    float s = p;
    #pragma unroll
    for (int off = 32; off > 0; off >>= 1) s += __shfl_xor(s, off);
    if (lane == 0) red[w] = s;
    __syncthreads();
    s = red[0] + red[1] + red[2] + red[3];

    attn[((size_t)b*CC_ + c)*CC_ + d] = p / s;
}

// ---------------------------------------------------------------------------
// K4: CAM apply: feats[b][256+c][n] = gamma_c * sum_d attn[c][d]*x[d][n] + x[c][n]
// attn reads wave-uniform -> scalar loads.
__global__ __launch_bounds__(256) void cam_apply_kernel(
    const float* __restrict__ x, const float* __restrict__ attn,
    const float* __restrict__ gamma_c, float* __restrict__ feats)
{
    const int tid = threadIdx.x;
    const int n  = blockIdx.x * 256 + tid;
    const int c0 = blockIdx.y * 32;
    const int b  = blockIdx.z;
    const float* A  = attn + ((size_t)b*CC_ + c0)*CC_;
    const float* xb = x + (size_t)b*CC_*NN_;

    float acc[32];
    #pragma unroll
    for (int r = 0; r < 32; r++) acc[r] = 0.f;

    #pragma unroll 4
    for (int dd = 0; dd < CC_; dd++) {
        float xv = xb[(size_t)dd*NN_ + n];
        #pragma unroll
        for (int r = 0; r < 32; r++)
            acc[r] = fmaf(A[r*CC_ + dd], xv, acc[r]);
    }
    const float gc = gamma_c[0];
    #pragma unroll
    for (int r = 0; r < 32; r++)
        feats[((size_t)b*2*CC_ + CC_ + c0 + r)*NN_ + n] =
            gc*acc[r] + xb[(size_t)(c0+r)*NN_ + n];
}

// ---------------------------------------------------------------------------
// K5: PAM flash attention, m-split (flash-decoding). q-tile 64, m-tile 32,
// 512 threads (8 waves). blockIdx.z = split s; each split covers m_len keys.
// Writes UNNORMALIZED O-partials + per-row (m,l); combine kernel merges.
// lane<->m mapping: mm = lane&31, ih = lane>>5; wave w owns q rows 8w..8w+7.
__global__ __launch_bounds__(512) void pam_flash_kernel(
    const float* __restrict__ qT, const float* __restrict__ kT,
    const float* __restrict__ vT,
    float* __restrict__ Opart, float2* __restrict__ ml2, int m_len)
{
    const int tid  = threadIdx.x;
    const int w    = tid >> 6, lane = tid & 63;
    const int n0   = blockIdx.x * 64;
    const int b    = blockIdx.y;
    const int s    = blockIdx.z;
    const int mm   = lane & 31, ih = lane >> 5;
    const int m_lo = s * m_len;
    const int m_hi = m_lo + m_len;

    __shared__ float q_t[32*64];    // q_t[r][row]
    __shared__ float k_l[32*32];    // XOR-swizzled: k[row][r] at row*32 + (r^row)
    __shared__ float P_l[64*32];    // P[row][mm], wave-private rows
    __shared__ float v_l[32*256];   // v tile, linear

    for (int idx = tid; idx < 2048; idx += 512) {
        int row = idx & 63, r = idx >> 6;
        q_t[r*64 + row] = qT[((size_t)b*NN_ + n0 + row)*32 + r];
    }

    float O[8][4];
    #pragma unroll
    for (int i = 0; i < 8; i++) { O[i][0]=O[i][1]=O[i][2]=O[i][3]=0.f; }
    float m_run[8], l_run[8];
    #pragma unroll
    for (int i = 0; i < 8; i++) { m_run[i] = -INFINITY; l_run[i] = 0.f; }

    for (int m0 = m_lo; m0 < m_hi; m0 += 32) {
        __syncthreads();
        for (int idx = tid; idx < 1024; idx += 512) {
            int row = idx >> 5, r = idx & 31;
            k_l[row*32 + (r ^ row)] = kT[((size_t)b*NN_ + m0 + row)*32 + r];
        }
        for (int idx = tid; idx < 2048; idx += 512) {
            int row = idx >> 6, q = idx & 63;
            *(float4*)&v_l[row*256 + 4*q] =
                *(const float4*)&vT[((size_t)b*NN_ + m0 + row)*CC_ + 4*q];
        }
        __syncthreads();

        // S[ii] = energy[n0 + 8w + 4ih + ii][m0 + mm]
        float S[4] = {0.f, 0.f, 0.f, 0.f};
        #pragma unroll 8
        for (int r = 0; r < 32; r++) {
            float kv = k_l[mm*32 + (r ^ mm)];
            float4 q4 = *(const float4*)&q_t[r*64 + 8*w + 4*ih];
            S[0] = fmaf(q4.x, kv, S[0]);
            S[1] = fmaf(q4.y, kv, S[1]);
            S[2] = fmaf(q4.z, kv, S[2]);
            S[3] = fmaf(q4.w, kv, S[3]);
        }

        // online softmax (half-wave = 32 lanes hold one row)
        float tmax[4], tsum[4], pv[4];
        #pragma unroll
        for (int ii = 0; ii < 4; ii++) {
            float mloc = S[ii];
            #pragma unroll
            for (int off = 16; off > 0; off >>= 1) mloc = fmaxf(mloc, __shfl_xor(mloc, off));
            tmax[ii] = mloc;
        }
        float scale[8];
        #pragma unroll
        for (int i = 0; i < 8; i++) {
            float mt = __shfl(tmax[i & 3], (i >> 2) << 5);
            float mn = fmaxf(m_run[i], mt);
            scale[i] = __expf(m_run[i] - mn);
            m_run[i] = mn;
        }
        #pragma unroll
        for (int ii = 0; ii < 4; ii++) {
            pv[ii] = __expf(S[ii] - m_run[4*ih + ii]);
            float sl = pv[ii];
            #pragma unroll
            for (int off = 16; off > 0; off >>= 1) sl += __shfl_xor(sl, off);
            tsum[ii] = sl;
        }
        #pragma unroll
        for (int i = 0; i < 8; i++) {
            float ts = __shfl(tsum[i & 3], (i >> 2) << 5);
            l_run[i] = l_run[i]*scale[i] + ts;
            #pragma unroll
            for (int j = 0; j < 4; j++) O[i][j] *= scale[i];
        }
        #pragma unroll
        for (int ii = 0; ii < 4; ii++)
            P_l[(8*w + 4*ih + ii)*32 + mm] = pv[ii];
        // P_l rows are wave-private; same-array ds ordering handled by compiler

        // PV: O[i][j] += sum_mm P[row_i][mm] * v[mm][4*lane + j]
        // P reads are wave-uniform -> LDS broadcast (conflict-free)
        #pragma unroll 2
        for (int mmb = 0; mmb < 32; mmb += 4) {
            float V[4][4];
            #pragma unroll
            for (int u = 0; u < 4; u++) {
                float4 vv = *(const float4*)&v_l[(mmb+u)*256 + 4*lane];
                V[u][0]=vv.x; V[u][1]=vv.y; V[u][2]=vv.z; V[u][3]=vv.w;
            }
            #pragma unroll
            for (int i = 0; i < 8; i++) {
                float4 p4 = *(const float4*)&P_l[(8*w + i)*32 + mmb];
                float P4[4] = {p4.x, p4.y, p4.z, p4.w};
                #pragma unroll
                for (int u = 0; u < 4; u++)
                    #pragma unroll
                    for (int j = 0; j < 4; j++)
                        O[i][j] = fmaf(P4[u], V[u][j], O[i][j]);
            }
        }
    }

    // write unnormalized partials, coalesced over lane (cols)
    const size_t obase = (((size_t)s*BB_ + b)*NN_ + n0)*CC_;
    #pragma unroll
    for (int i = 0; i < 8; i++)
        *(float4*)&Opart[obase + (size_t)(8*w + i)*CC_ + 4*lane] =
            make_float4(O[i][0], O[i][1], O[i][2], O[i][3]);
    if (lane == 0) {
        #pragma unroll
        for (int i = 0; i < 8; i++)
            ml2[((size_t)s*BB_ + b)*NN_ + n0 + 8*w + i] =
                make_float2(m_run[i], l_run[i]);
    }
}

// ---------------------------------------------------------------------------
// K5b: combine m-splits, normalize, apply gamma_p + residual, write feats[0:256].
__global__ __launch_bounds__(512) void pam_combine_kernel(
    const float* __restrict__ x, const float* __restrict__ Opart,
    const float2* __restrict__ ml2, const float* __restrict__ gamma_p,
    float* __restrict__ feats, int S)
{
    const int tid = threadIdx.x;
    const int n0  = blockIdx.x * 64;
    const int b   = blockIdx.y;

    __shared__ float wsc[2*64];     // [s][row]: exp(m_s - M) / denom
    __shared__ float tile[64*65];   // [c_local][row]

    if (tid < 64) {
        float mv[2], lv[2];
        for (int s = 0; s < S; s++) {
            float2 t = ml2[((size_t)s*BB_ + b)*NN_ + n0 + tid];
            mv[s] = t.x; lv[s] = t.y;
        }
        float M = mv[0];
        for (int s = 1; s < S; s++) M = fmaxf(M, mv[s]);
        float denom = 0.f;
        for (int s = 0; s < S; s++) denom += lv[s] * __expf(mv[s] - M);
        float inv = 1.f / denom;
        for (int s = 0; s < S; s++) wsc[s*64 + tid] = __expf(mv[s] - M) * inv;
    }
    __syncthreads();

    const float gp = gamma_p[0];
    for (int cb = 0; cb < 4; cb++) {
        if (cb) __syncthreads();
        #pragma unroll 1
        for (int p = 0; p < 8; p++) {
            int row = p*8 + (tid >> 6);
            int c   = cb*64 + (tid & 63);
            float v = 0.f;
            for (int s = 0; s < S; s++)
                v += Opart[(((size_t)s*BB_ + b)*NN_ + n0 + row)*CC_ + c] * wsc[s*64 + row];
            tile[(tid & 63)*65 + row] = v;
        }
        __syncthreads();
        for (int idx = tid; idx < 4096; idx += 512) {
            int c_l = idx >> 6, nn = idx & 63;
            int chn = cb*64 + c_l;
            feats[((size_t)b*2*CC_ + chn)*NN_ + n0 + nn] =
                gp * tile[c_l*65 + nn] + x[((size_t)b*CC_ + chn)*NN_ + n0 + nn];
        }
    }
}

// ---------------------------------------------------------------------------
// K6: fuse conv3x3 (512 -> 256, pad 1, no bias). feats -> y (d_out).
// 8x64 spatial tile, 1024 blocks (4/CU), div-free staging, stride-67 patch.
__global__ __launch_bounds__(256, 4) void conv_kernel(
    const float* __restrict__ feats, const float* __restrict__ fuse_w,
    float* __restrict__ y)
{
    const int tid = threadIdx.x;
    const int tx = tid & 15;
    const int ty = tid >> 4;
    const int row = ty & 7;
    const int och = ty >> 3;           // 0 or 1, wave-uniform
    const int tile_y = blockIdx.x * 8;
    const int o0 = blockIdx.y * 8;
    const int b = blockIdx.z;

    __shared__ float patch[4*10*67];   // [ic][yy][67]; col0 & col65/66 stay 0
    __shared__ float wl[9*4*8];        // [k][ic][oc8]

    for (int idx = tid; idx < 4*10*67; idx += 256) patch[idx] = 0.f;

    float acc[4][4];
    #pragma unroll
    for (int oo = 0; oo < 4; oo++) { acc[oo][0]=acc[oo][1]=acc[oo][2]=acc[oo][3]=0.f; }

    const int wv   = tid >> 6;         // wave id = ic slot, 0..3
    const int lane = tid & 63;         // gx

    for (int i0 = 0; i0 < 512; i0 += 4) {
        __syncthreads();
        {
            const float* src = &feats[(((size_t)b*512 + i0 + wv)*64)*64 + lane];
            float* dstl = &patch[(wv*10)*67 + lane + 1];
            #pragma unroll
            for (int k = 0; k < 10; k++) {
                int gy = tile_y - 1 + k;
                float v = 0.f;
                if ((unsigned)gy < 64u) v = src[(size_t)gy*64];
                dstl[k*67] = v;
            }
        }
        for (int idx = tid; idx < 288; idx += 256) {
            int oc8 = idx & 7, rem = idx >> 3;
            int ic = rem & 3, k = rem >> 2;
            wl[(k*4 + ic)*8 + oc8] =
                fuse_w[(size_t)(o0 + oc8)*4608 + (size_t)(i0 + ic)*9 + k];
        }
        __syncthreads();

        #pragma unroll
        for (int ic = 0; ic < 4; ic++) {
            float px[3][6];
            #pragma unroll
            for (int dy = 0; dy < 3; dy++) {
                const float* pr = &patch[(ic*10 + row + dy)*67 + 4*tx];
                #pragma unroll
                for (int j = 0; j < 6; j++) px[dy][j] = pr[j];
            }
            #pragma unroll
            for (int dy = 0; dy < 3; dy++)
                #pragma unroll
                for (int dx = 0; dx < 3; dx++) {
                    float4 w4 = *(const float4*)&wl[((dy*3 + dx)*4 + ic)*8 + 4*och];
                    float wv4[4] = {w4.x, w4.y, w4.z, w4.w};
                    #pragma unroll
                    for (int oo = 0; oo < 4; oo++)
                        #pragma unroll
                        for (int p = 0; p < 4; p++)
                            acc[oo][p] = fmaf(wv4[oo], px[dy][dx + p], acc[oo][p]);
                }
        }
    }

    #pragma unroll
    for (int oo = 0; oo < 4; oo++)
        *(float4*)&y[(((size_t)b*CC_ + o0 + 4*och + oo)*64 + tile_y + row)*64 + 4*tx] =
            make_float4(acc[oo][0], acc[oo][1], acc[oo][2], acc[oo][3]);
}

// ---------------------------------------------------------------------------
// K7: BN batch stats per channel (no atomics: one block per channel).
__global__ __launch_bounds__(256) void bn_stats_kernel(
    const float* __restrict__ y, const float* __restrict__ bn_scale,
    const float* __restrict__ bn_bias, float* __restrict__ stats)
{
    const int c = blockIdx.x;
    const int tid = threadIdx.x;
    const int lane = tid & 63, w = tid >> 6;
    float s = 0.f, q = 0.f;
    for (int b = 0; b < 4; b++) {
        const float4* p = (const float4*)(y + ((size_t)b*CC_ + c)*NN_);
        for (int i = tid; i < 1024; i += 256) {
            float4 v = p[i];
            s += v.x + v.y + v.z + v.w;
            q += v.x*v.x + v.y*v.y + v.z*v.z + v.w*v.w;
        }
    }
    #pragma unroll
    for (int off = 32; off > 0; off >>= 1) { s += __shfl_xor(s, off); q += __shfl_xor(q, off); }
    __shared__ float rs[4], rq[4];
    if (lane == 0) { rs[w] = s; rq[w] = q; }
    __syncthreads();
    if (tid == 0) {
        float S = rs[0]+rs[1]+rs[2]+rs[3];
        float Q = rq[0]+rq[1]+rq[2]+rq[3];
        const float inv_n = 1.f / 16384.f;
        float mean = S * inv_n;
        float var  = Q * inv_n - mean*mean;
        float sc = bn_scale[c] * rsqrtf(var + 1e-5f);
        stats[c]       = sc;
        stats[CC_ + c] = bn_bias[c] - mean * sc;
    }
}

// K8: BN apply + ReLU, in place on d_out.
__global__ __launch_bounds__(256) void bn_apply_kernel(
    float* __restrict__ y, const float* __restrict__ stats)
{
    const int f = blockIdx.x*256 + threadIdx.x;   // float4 index, 1048576 total
    const int c = (f >> 10) & 255;
    const float sc = stats[c], sh = stats[CC_ + c];
    float4 v = ((float4*)y)[f];
    v.x = fmaxf(fmaf(v.x, sc, sh), 0.f);
    v.y = fmaxf(fmaf(v.y, sc, sh), 0.f);
    v.z = fmaxf(fmaf(v.z, sc, sh), 0.f);
    v.w = fmaxf(fmaf(v.w, sc, sh), 0.f);
    ((float4*)y)[f] = v;
}

// ---------------------------------------------------------------------------
extern "C" void kernel_launch(void* const* d_in, const int* in_sizes, int n_in,
                              void* d_out, int out_size, void* d_ws, size_t ws_size,
                              hipStream_t stream)
{
    const float* x        = (const float*)d_in[0];
    const float* q_w      = (const float*)d_in[1];
    const float* q_b      = (const float*)d_in[2];
    const float* k_w      = (const float*)d_in[3];
    const float* k_b      = (const float*)d_in[4];
    const float* v_w      = (const float*)d_in[5];
    const float* v_b      = (const float*)d_in[6];
    const float* gamma_p  = (const float*)d_in[7];
    const float* gamma_c  = (const float*)d_in[8];
    const float* fuse_w   = (const float*)d_in[9];
    const float* bn_scale = (const float*)d_in[10];
    const float* bn_bias  = (const float*)d_in[11];
    float* out = (float*)d_out;

    float* ws    = (float*)d_ws;
    float* qT    = ws;                               //   524288 f
    float* kT    = qT    + (size_t)BB_*NN_*32;       //   524288 f
    float* vT    = kT    + (size_t)BB_*NN_*32;       //  4194304 f
    float* feats = vT    + (size_t)BB_*NN_*CC_;      //  8388608 f
    float* R     = feats + (size_t)BB_*2*CC_*NN_;    // phase-shared region
    // CAM phase:  R = e_part (4194304 f) | attn (262144 f)
    // PAM phase:  R = Opart (S*4194304 f) | ml2 (S*32768 f)  [e_part/attn dead]
    float* e_part = R;
    float* attn   = R + (size_t)BB_*16*CC_*CC_;

    // m-split factor: 2 if workspace allows, else 1 (same code path).
    const size_t fixed_f = (size_t)13631488;  // qT..feats
    int S = (ws_size >= (fixed_f + 2u*4194304u + 2u*32768u + 512u)*sizeof(float)) ? 2 : 1;
    float*  Opart = R;
    float2* ml2   = (float2*)(R + (size_t)S*BB_*NN_*CC_);
    float*  stats = R + (size_t)S*BB_*NN_*CC_ + (size_t)S*BB_*NN_*2;

    hipLaunchKernelGGL(qkv_kernel, dim3(16,10,BB_), dim3(256), 0, stream,
                       x, q_w, q_b, k_w, k_b, v_w, v_b, qT, kT, vT);
    hipLaunchKernelGGL(cam_energy_kernel, dim3(16,16,BB_), dim3(64), 0, stream,
                       x, e_part);
    hipLaunchKernelGGL(cam_softmax_kernel, dim3(CC_,BB_), dim3(256), 0, stream,
                       e_part, attn);
    hipLaunchKernelGGL(cam_apply_kernel, dim3(16,8,BB_), dim3(256), 0, stream,
                       x, attn, gamma_c, feats);
    hipLaunchKernelGGL(pam_flash_kernel, dim3(64,BB_,S), dim3(512), 0, stream,
                       qT, kT, vT, Opart, ml2, NN_/S);
    hipLaunchKernelGGL(pam_combine_kernel, dim3(64,BB_), dim3(512), 0, stream,
                       x, Opart, ml2, gamma_p, feats, S);
    hipLaunchKernelGGL(conv_kernel, dim3(8,32,BB_), dim3(256), 0, stream,
                       feats, fuse_w, out);
    hipLaunchKernelGGL(bn_stats_kernel, dim3(CC_), dim3(256), 0, stream,
                       out, bn_scale, bn_bias, stats);
    hipLaunchKernelGGL(bn_apply_kernel, dim3(4096), dim3(256), 0, stream,
                       out, stats);
}